// Round 10
// baseline (133.102 us; speedup 1.0000x reference)
//
#include <hip/hip_runtime.h>
#include <math.h>

#define G_MAX 128
#define D 64
#define NB 1024         // blocks for the fused scatter
#define CAP 32768       // per-graph bucket capacity (mean ~9766, sigma ~98)
#define CAP_SHIFT 15
#define LGID_MAX 2048   // per-block chunk capacity (chunk = ceil(E/NB) = 1221)
#define EBPS 16         // edge-gather blocks per graph  (power of 2)
#define EBPS_SHIFT 4
#define VBPS 4          // vertex-gather blocks per graph (power of 2)
#define VBPS_SHIFT 2
#define WPB 4           // waves per 256-thread block
#define UNR 8           // rows in flight per lane in the gather

typedef float vfloat4 __attribute__((ext_vector_type(4)));

__device__ __forceinline__ float4 ntload4(const float* p) {
    vfloat4 v = __builtin_nontemporal_load(reinterpret_cast<const vfloat4*>(p));
    return make_float4(v.x, v.y, v.z, v.w);
}

// ---- K1 (fused): per-block hist -> global bucket reservation -> scatter ----
// Blocks [0, NB): counting-scatter of edge ids into fixed-capacity buckets.
// Block NB: vertex-range binary searches (independent work, same launch).
__global__ __launch_bounds__(256) void k_fused_scatter(
    const int* __restrict__ src, const int* __restrict__ batch, int E,
    unsigned* __restrict__ ecnt /* zeroed before launch */,
    int* __restrict__ sorted_eid /* [G_MAX*CAP] */,
    int N, int* __restrict__ vstart)
{
    int t = threadIdx.x;
    if (blockIdx.x == NB) {
        if (t <= G_MAX) {
            int lo = 0, hi = N;
            while (lo < hi) {
                int mid = (lo + hi) >> 1;
                if (batch[mid] < t) lo = mid + 1; else hi = mid;
            }
            vstart[t] = lo;
        }
        return;
    }

    __shared__ unsigned hist[G_MAX];
    __shared__ unsigned lcur[G_MAX];
    __shared__ unsigned char lgid[LGID_MAX];

    for (int i = t; i < G_MAX; i += blockDim.x) hist[i] = 0u;
    __syncthreads();

    const int chunk = (E + NB - 1) / NB;
    const int begin = blockIdx.x * chunk;
    const int end   = min(E, begin + chunk);

    for (int e = begin + t; e < end; e += blockDim.x) {
        int g = batch[src[e]];
        lgid[e - begin] = (unsigned char)g;
        atomicAdd(&hist[g], 1u);
    }
    __syncthreads();

    // reserve [base, base+hist[g]) in graph g's bucket
    for (int i = t; i < G_MAX; i += blockDim.x) {
        unsigned h = hist[i];
        lcur[i] = h ? atomicAdd(&ecnt[i], h) : 0u;
    }
    __syncthreads();

    for (int e = begin + t; e < end; e += blockDim.x) {
        int g = lgid[e - begin];
        unsigned pos = atomicAdd(&lcur[g], 1u);
        if (pos < CAP) sorted_eid[((size_t)g << CAP_SHIFT) + pos] = e;
    }
}

// ---------------- K2: combined register-accumulated gather reduction --------
__device__ __forceinline__ float4 f4shfl_xor(float4 v, int m) {
    return make_float4(__shfl_xor(v.x, m, 64), __shfl_xor(v.y, m, 64),
                       __shfl_xor(v.z, m, 64), __shfl_xor(v.w, m, 64));
}
__device__ __forceinline__ float4 f4add(float4 a, float4 b) {
    return make_float4(a.x + b.x, a.y + b.y, a.z + b.z, a.w + b.w);
}
__device__ __forceinline__ void acc4(float4 v, float4& mn, float4& mx, float4& sm) {
    mn.x = fminf(mn.x, v.x); mn.y = fminf(mn.y, v.y); mn.z = fminf(mn.z, v.z); mn.w = fminf(mn.w, v.w);
    mx.x = fmaxf(mx.x, v.x); mx.y = fmaxf(mx.y, v.y); mx.z = fmaxf(mx.z, v.z); mx.w = fmaxf(mx.w, v.w);
    sm.x += v.x; sm.y += v.y; sm.z += v.z; sm.w += v.w;
}

__global__ __launch_bounds__(256) void k_gather_stats(
    const float* __restrict__ e_attr_, const int* __restrict__ s_eid,
    const unsigned* __restrict__ ecnt,
    const float* __restrict__ v_attr_, const int* __restrict__ vstart,
    float* __restrict__ pe_min, float* __restrict__ pe_max, float* __restrict__ pe_sum,
    float* __restrict__ pv_min, float* __restrict__ pv_max, float* __restrict__ pv_sum)
{
    __shared__ float lmin[WPB][D], lmax[WPB][D], lsum[WPB][D];
    const int b = blockIdx.x;
    const bool isE = (b < G_MAX * EBPS);
    const float* attr = isE ? e_attr_ : v_attr_;
    const int*  idx   = isE ? s_eid : nullptr;
    float* pmin = isE ? pe_min : pv_min;
    float* pmax = isE ? pe_max : pv_max;
    float* psum = isE ? pe_sum : pv_sum;
    const int bid   = isE ? b : (b - G_MAX * EBPS);
    const int shift = isE ? EBPS_SHIFT : VBPS_SHIFT;
    const int bps   = 1 << shift;
    const int g     = bid >> shift;
    const int sub   = bid & (bps - 1);

    int start, end;
    if (isE) {
        start = g << CAP_SHIFT;
        end   = start + (int)min(ecnt[g], (unsigned)CAP);
    } else {
        start = vstart[g];
        end   = vstart[g + 1];
    }

    const int lane = threadIdx.x & 63, w = threadIdx.x >> 6;
    const int q = lane >> 4;          // which of 4 row streams this lane covers
    const int p = lane & 15;          // 4-feature chunk within row
    const int wg = sub * WPB + w;     // global wave index within this graph
    const int stride = bps * WPB * (4 * UNR); // rows per wave per iteration

    float4 mn = make_float4(INFINITY, INFINITY, INFINITY, INFINITY);
    float4 mx = make_float4(-INFINITY, -INFINITY, -INFINITY, -INFINITY);
    float4 sm = make_float4(0.f, 0.f, 0.f, 0.f);

    for (int e = start + wg * (4 * UNR) + q; e < end; e += stride) {
        int  rid[UNR];
        bool ok[UNR];
        #pragma unroll
        for (int j = 0; j < UNR; ++j) {
            int ej = e + 4 * j;
            ok[j]  = ej < end;                       // ok[0] always true
            rid[j] = ok[j] ? (idx ? idx[ej] : ej) : (idx ? idx[e] : e);
        }
        float4 v[UNR];
        #pragma unroll
        for (int j = 0; j < UNR; ++j)
            v[j] = ntload4(&attr[(size_t)rid[j] * D + p * 4]);
        #pragma unroll
        for (int j = 0; j < UNR; ++j)
            if (ok[j]) acc4(v[j], mn, mx, sm);
    }

    // reduce the 4 q-groups (row streams) down to q==0 lanes
    float4 o;
    o = f4shfl_xor(mn, 16);
    mn.x = fminf(mn.x, o.x); mn.y = fminf(mn.y, o.y); mn.z = fminf(mn.z, o.z); mn.w = fminf(mn.w, o.w);
    o = f4shfl_xor(mn, 32);
    mn.x = fminf(mn.x, o.x); mn.y = fminf(mn.y, o.y); mn.z = fminf(mn.z, o.z); mn.w = fminf(mn.w, o.w);
    o = f4shfl_xor(mx, 16);
    mx.x = fmaxf(mx.x, o.x); mx.y = fmaxf(mx.y, o.y); mx.z = fmaxf(mx.z, o.z); mx.w = fmaxf(mx.w, o.w);
    o = f4shfl_xor(mx, 32);
    mx.x = fmaxf(mx.x, o.x); mx.y = fmaxf(mx.y, o.y); mx.z = fmaxf(mx.z, o.z); mx.w = fmaxf(mx.w, o.w);
    sm = f4add(sm, f4shfl_xor(sm, 16));
    sm = f4add(sm, f4shfl_xor(sm, 32));

    if (q == 0) {
        lmin[w][p*4+0] = mn.x; lmin[w][p*4+1] = mn.y; lmin[w][p*4+2] = mn.z; lmin[w][p*4+3] = mn.w;
        lmax[w][p*4+0] = mx.x; lmax[w][p*4+1] = mx.y; lmax[w][p*4+2] = mx.z; lmax[w][p*4+3] = mx.w;
        lsum[w][p*4+0] = sm.x; lsum[w][p*4+1] = sm.y; lsum[w][p*4+2] = sm.z; lsum[w][p*4+3] = sm.w;
    }
    __syncthreads();
    int t = threadIdx.x;
    if (t < D) {
        float a  = fminf(fminf(lmin[0][t], lmin[1][t]), fminf(lmin[2][t], lmin[3][t]));
        float b2 = fmaxf(fmaxf(lmax[0][t], lmax[1][t]), fmaxf(lmax[2][t], lmax[3][t]));
        float c  = lsum[0][t] + lsum[1][t] + lsum[2][t] + lsum[3][t];
        size_t o2 = ((size_t)g * bps + sub) * D + t;
        pmin[o2] = a; pmax[o2] = b2; psum[o2] = c;
    }
}

// ---------------- K3: combine partials -> 576-row -> MLP --------------------
__global__ __launch_bounds__(256) void k_finalize_mlp(
    const float* __restrict__ g_in,
    const float* __restrict__ pe_min, const float* __restrict__ pe_max, const float* __restrict__ pe_sum,
    const float* __restrict__ pv_min, const float* __restrict__ pv_max, const float* __restrict__ pv_sum,
    const unsigned* __restrict__ ecnt, const int* __restrict__ vstart,
    const float* __restrict__ W1, const float* __restrict__ b1,
    const float* __restrict__ W2, const float* __restrict__ b2,
    float* __restrict__ out, int n_in, int n_hid, int n_out)
{
    __shared__ float row[576];
    __shared__ float h[256];
    int gi = blockIdx.x;
    int t = threadIdx.x;

    if (t < D) {
        float mn = INFINITY, mx = -INFINITY, sm = 0.f;
        #pragma unroll 8
        for (int s = 0; s < EBPS; ++s) {
            size_t o = ((size_t)gi * EBPS + s) * D + t;
            mn = fminf(mn, pe_min[o]); mx = fmaxf(mx, pe_max[o]); sm += pe_sum[o];
        }
        float cnt = (float)ecnt[gi];
        row[64 + t]  = mn;
        row[128 + t] = sm / fmaxf(cnt, 1.0f);
        row[192 + t] = sm;
        row[256 + t] = mx;

        float vmn = INFINITY, vmx = -INFINITY, vsm = 0.f;
        #pragma unroll
        for (int s = 0; s < VBPS; ++s) {
            size_t o = ((size_t)gi * VBPS + s) * D + t;
            vmn = fminf(vmn, pv_min[o]); vmx = fmaxf(vmx, pv_max[o]); vsm += pv_sum[o];
        }
        float vcnt = (float)(vstart[gi + 1] - vstart[gi]);
        row[320 + t] = vmn;
        row[384 + t] = vsm / fmaxf(vcnt, 1.0f);
        row[448 + t] = vsm;
        row[512 + t] = vmx;

        row[t] = g_in[gi * D + t];
    }
    __syncthreads();

    for (int j = t; j < n_hid; j += blockDim.x) {
        float acc = b1[j];
        #pragma unroll 8
        for (int k = 0; k < n_in; ++k) acc = fmaf(row[k], W1[k * n_hid + j], acc);
        h[j] = fmaxf(acc, 0.0f);
    }
    __syncthreads();

    for (int j = t; j < n_out; j += blockDim.x) {
        float acc = b2[j];
        #pragma unroll 8
        for (int k = 0; k < n_hid; ++k) acc = fmaf(h[k], W2[k * n_out + j], acc);
        out[gi * n_out + j] = acc;
    }
}

extern "C" void kernel_launch(void* const* d_in, const int* in_sizes, int n_in_args,
                              void* d_out, int out_size, void* d_ws, size_t ws_size,
                              hipStream_t stream) {
    const float* v_attr    = (const float*)d_in[0];
    const int*   edge_pair = (const int*)d_in[1];   // [2, E]; row 0 = src
    const float* e_attr    = (const float*)d_in[2];
    const float* g_in      = (const float*)d_in[3];
    const int*   batch     = (const int*)d_in[4];
    const float* W1        = (const float*)d_in[5];
    const float* b1        = (const float*)d_in[6];
    const float* W2        = (const float*)d_in[7];
    const float* b2        = (const float*)d_in[8];

    int N  = in_sizes[4];
    int E  = in_sizes[1] / 2;
    int nh = in_sizes[6];            // 256
    int no = in_sizes[8];            // 64
    int ni = in_sizes[5] / nh;       // 576

    // ---- ws bump allocation (256B aligned) ----
    char* p = (char*)d_ws;
    auto alloc = [&](size_t bytes) {
        char* r = p;
        p += (bytes + 255) & ~(size_t)255;
        return r;
    };
    unsigned* ecnt   = (unsigned*)alloc((size_t)G_MAX * 4);
    int*      vstart = (int*)alloc((size_t)(G_MAX + 1) * 4);
    int*      s_eid  = (int*)alloc((size_t)G_MAX * CAP * 4);   // 16 MB
    float*    pe_min = (float*)alloc((size_t)G_MAX * EBPS * D * 4);
    float*    pe_max = (float*)alloc((size_t)G_MAX * EBPS * D * 4);
    float*    pe_sum = (float*)alloc((size_t)G_MAX * EBPS * D * 4);
    float*    pv_min = (float*)alloc((size_t)G_MAX * VBPS * D * 4);
    float*    pv_max = (float*)alloc((size_t)G_MAX * VBPS * D * 4);
    float*    pv_sum = (float*)alloc((size_t)G_MAX * VBPS * D * 4);

    hipMemsetAsync(ecnt, 0, (size_t)G_MAX * 4, stream);

    // fused hist+reserve+scatter (blocks 0..NB-1) + vstart search (block NB)
    k_fused_scatter<<<NB + 1, 256, 0, stream>>>(
        edge_pair, batch, E, ecnt, s_eid, N, vstart);

    // combined edge + vertex gather (edges: via bucketed id list; vertices: contiguous)
    k_gather_stats<<<G_MAX * EBPS + G_MAX * VBPS, 256, 0, stream>>>(
        e_attr, s_eid, ecnt, v_attr, vstart,
        pe_min, pe_max, pe_sum, pv_min, pv_max, pv_sum);

    k_finalize_mlp<<<G_MAX, 256, 0, stream>>>(g_in,
        pe_min, pe_max, pe_sum, pv_min, pv_max, pv_sum,
        ecnt, vstart, W1, b1, W2, b2,
        (float*)d_out, ni, nh, no);
}

// Round 11
// 127.488 us; speedup vs baseline: 1.0440x; 1.0440x over previous
//
#include <hip/hip_runtime.h>
#include <math.h>

#define G_MAX 128
#define D 64
#define NB 1024         // blocks for hist/scatter chunking
#define EBPS 16         // edge-gather blocks per graph  (power of 2)
#define EBPS_SHIFT 4
#define VBPS 4          // vertex-gather blocks per graph (power of 2)
#define VBPS_SHIFT 2
#define WPB 4           // waves per 256-thread block
#define UNR 8           // rows in flight per lane in the gather

typedef float vfloat4 __attribute__((ext_vector_type(4)));

__device__ __forceinline__ float4 ntload4(const float* p) {
    vfloat4 v = __builtin_nontemporal_load(reinterpret_cast<const vfloat4*>(p));
    return make_float4(v.x, v.y, v.z, v.w);
}

// ---------------- K1: edge segment ids + per-block histogram ----------------
__global__ __launch_bounds__(256) void k_eseg_hist(
    const int* __restrict__ src, const int* __restrict__ batch, int E,
    unsigned char* __restrict__ eseg, unsigned* __restrict__ counts /*[G_MAX][NB]*/)
{
    __shared__ unsigned hist[G_MAX];
    for (int i = threadIdx.x; i < G_MAX; i += blockDim.x) hist[i] = 0u;
    __syncthreads();
    int chunk = (E + NB - 1) / NB;
    int begin = blockIdx.x * chunk;
    int end   = min(E, begin + chunk);
    for (int e = begin + threadIdx.x; e < end; e += blockDim.x) {
        int g = batch[src[e]];
        eseg[e] = (unsigned char)g;
        atomicAdd(&hist[g], 1u);
    }
    __syncthreads();
    for (int i = threadIdx.x; i < G_MAX; i += blockDim.x)
        counts[(size_t)i * NB + blockIdx.x] = hist[i];
}

// ------------- K2a: per-graph exclusive scan of NB block counts -------------
__global__ __launch_bounds__(256) void k_scan_counts(
    unsigned* __restrict__ counts, unsigned* __restrict__ gtot)
{
    __shared__ unsigned s[256];
    unsigned* c = counts + (size_t)blockIdx.x * NB;
    int t = threadIdx.x;
    unsigned v0 = c[4*t], v1 = c[4*t+1], v2 = c[4*t+2], v3 = c[4*t+3];
    s[t] = v0 + v1 + v2 + v3;
    __syncthreads();
    for (int off = 1; off < 256; off <<= 1) {
        unsigned x = (t >= off) ? s[t - off] : 0u;
        __syncthreads();
        s[t] += x;
        __syncthreads();
    }
    unsigned base = (t > 0) ? s[t - 1] : 0u;
    c[4*t]   = base;
    c[4*t+1] = base + v0;
    c[4*t+2] = base + v0 + v1;
    c[4*t+3] = base + v0 + v1 + v2;
    if (t == 255) gtot[blockIdx.x] = s[255];
}

// ---- K2b: graph bucket bases (cbase) + vertex ranges via binary search ----
__global__ __launch_bounds__(256) void k_bounds(
    const unsigned* __restrict__ gtot, const int* __restrict__ batch, int N,
    int* __restrict__ cbase, int* __restrict__ vstart)
{
    int t = threadIdx.x;
    if (t == 0) {
        int acc = 0;
        for (int g = 0; g < G_MAX; ++g) { cbase[g] = acc; acc += (int)gtot[g]; }
        cbase[G_MAX] = acc;
    }
    if (t <= G_MAX) {
        int lo = 0, hi = N;
        while (lo < hi) {
            int mid = (lo + hi) >> 1;
            if (batch[mid] < t) lo = mid + 1; else hi = mid;
        }
        vstart[t] = lo;
    }
}

// ---------------- K3: race-free scatter into per-graph buckets --------------
__global__ __launch_bounds__(256) void k_scatter(
    const unsigned char* __restrict__ eseg, const unsigned* __restrict__ counts,
    const int* __restrict__ cbase, int E, int* __restrict__ sorted_eid)
{
    __shared__ unsigned lcur[G_MAX];
    for (int i = threadIdx.x; i < G_MAX; i += blockDim.x)
        lcur[i] = (unsigned)cbase[i] + counts[(size_t)i * NB + blockIdx.x];
    __syncthreads();
    int chunk = (E + NB - 1) / NB;
    int begin = blockIdx.x * chunk;
    int end   = min(E, begin + chunk);
    for (int e = begin + threadIdx.x; e < end; e += blockDim.x) {
        int g = eseg[e];
        unsigned pos = atomicAdd(&lcur[g], 1u);
        sorted_eid[pos] = e;
    }
}

// ---------------- K4: combined register-accumulated gather reduction --------
__device__ __forceinline__ float4 f4shfl_xor(float4 v, int m) {
    return make_float4(__shfl_xor(v.x, m, 64), __shfl_xor(v.y, m, 64),
                       __shfl_xor(v.z, m, 64), __shfl_xor(v.w, m, 64));
}
__device__ __forceinline__ float4 f4add(float4 a, float4 b) {
    return make_float4(a.x + b.x, a.y + b.y, a.z + b.z, a.w + b.w);
}
__device__ __forceinline__ void acc4(float4 v, float4& mn, float4& mx, float4& sm) {
    mn.x = fminf(mn.x, v.x); mn.y = fminf(mn.y, v.y); mn.z = fminf(mn.z, v.z); mn.w = fminf(mn.w, v.w);
    mx.x = fmaxf(mx.x, v.x); mx.y = fmaxf(mx.y, v.y); mx.z = fmaxf(mx.z, v.z); mx.w = fmaxf(mx.w, v.w);
    sm.x += v.x; sm.y += v.y; sm.z += v.z; sm.w += v.w;
}

__global__ __launch_bounds__(256) void k_gather_stats(
    const float* __restrict__ e_attr_, const int* __restrict__ s_eid,
    const int* __restrict__ cbase,
    const float* __restrict__ v_attr_, const int* __restrict__ vstart,
    float* __restrict__ pe_min, float* __restrict__ pe_max, float* __restrict__ pe_sum,
    float* __restrict__ pv_min, float* __restrict__ pv_max, float* __restrict__ pv_sum)
{
    __shared__ float lmin[WPB][D], lmax[WPB][D], lsum[WPB][D];
    const int b = blockIdx.x;
    const bool isE = (b < G_MAX * EBPS);
    const float* attr  = isE ? e_attr_ : v_attr_;
    const int*  idx    = isE ? s_eid : nullptr;
    const int*  bounds = isE ? cbase : vstart;
    float* pmin = isE ? pe_min : pv_min;
    float* pmax = isE ? pe_max : pv_max;
    float* psum = isE ? pe_sum : pv_sum;
    const int bid   = isE ? b : (b - G_MAX * EBPS);
    const int shift = isE ? EBPS_SHIFT : VBPS_SHIFT;
    const int bps   = 1 << shift;
    const int g     = bid >> shift;
    const int sub   = bid & (bps - 1);

    const int start = bounds[g], end = bounds[g + 1];
    const int lane = threadIdx.x & 63, w = threadIdx.x >> 6;
    const int q = lane >> 4;          // which of 4 row streams this lane covers
    const int p = lane & 15;          // 4-feature chunk within row
    const int wg = sub * WPB + w;     // global wave index within this graph
    const int stride = bps * WPB * (4 * UNR); // rows per wave per iteration

    float4 mn = make_float4(INFINITY, INFINITY, INFINITY, INFINITY);
    float4 mx = make_float4(-INFINITY, -INFINITY, -INFINITY, -INFINITY);
    float4 sm = make_float4(0.f, 0.f, 0.f, 0.f);

    for (int e = start + wg * (4 * UNR) + q; e < end; e += stride) {
        int  rid[UNR];
        bool ok[UNR];
        #pragma unroll
        for (int j = 0; j < UNR; ++j) {
            int ej = e + 4 * j;
            ok[j]  = ej < end;                       // ok[0] always true
            rid[j] = ok[j] ? (idx ? idx[ej] : ej) : (idx ? idx[e] : e);
        }
        float4 v[UNR];
        #pragma unroll
        for (int j = 0; j < UNR; ++j)
            v[j] = ntload4(&attr[(size_t)rid[j] * D + p * 4]);
        #pragma unroll
        for (int j = 0; j < UNR; ++j)
            if (ok[j]) acc4(v[j], mn, mx, sm);
    }

    // reduce the 4 q-groups (row streams) down to q==0 lanes
    float4 o;
    o = f4shfl_xor(mn, 16);
    mn.x = fminf(mn.x, o.x); mn.y = fminf(mn.y, o.y); mn.z = fminf(mn.z, o.z); mn.w = fminf(mn.w, o.w);
    o = f4shfl_xor(mn, 32);
    mn.x = fminf(mn.x, o.x); mn.y = fminf(mn.y, o.y); mn.z = fminf(mn.z, o.z); mn.w = fminf(mn.w, o.w);
    o = f4shfl_xor(mx, 16);
    mx.x = fmaxf(mx.x, o.x); mx.y = fmaxf(mx.y, o.y); mx.z = fmaxf(mx.z, o.z); mx.w = fmaxf(mx.w, o.w);
    o = f4shfl_xor(mx, 32);
    mx.x = fmaxf(mx.x, o.x); mx.y = fmaxf(mx.y, o.y); mx.z = fmaxf(mx.z, o.z); mx.w = fmaxf(mx.w, o.w);
    sm = f4add(sm, f4shfl_xor(sm, 16));
    sm = f4add(sm, f4shfl_xor(sm, 32));

    if (q == 0) {
        lmin[w][p*4+0] = mn.x; lmin[w][p*4+1] = mn.y; lmin[w][p*4+2] = mn.z; lmin[w][p*4+3] = mn.w;
        lmax[w][p*4+0] = mx.x; lmax[w][p*4+1] = mx.y; lmax[w][p*4+2] = mx.z; lmax[w][p*4+3] = mx.w;
        lsum[w][p*4+0] = sm.x; lsum[w][p*4+1] = sm.y; lsum[w][p*4+2] = sm.z; lsum[w][p*4+3] = sm.w;
    }
    __syncthreads();
    int t = threadIdx.x;
    if (t < D) {
        float a  = fminf(fminf(lmin[0][t], lmin[1][t]), fminf(lmin[2][t], lmin[3][t]));
        float b2 = fmaxf(fmaxf(lmax[0][t], lmax[1][t]), fmaxf(lmax[2][t], lmax[3][t]));
        float c  = lsum[0][t] + lsum[1][t] + lsum[2][t] + lsum[3][t];
        size_t o2 = ((size_t)g * bps + sub) * D + t;
        pmin[o2] = a; pmax[o2] = b2; psum[o2] = c;
    }
}

// ---------------- K5: combine partials -> 576-row -> MLP --------------------
__global__ __launch_bounds__(256) void k_finalize_mlp(
    const float* __restrict__ g_in,
    const float* __restrict__ pe_min, const float* __restrict__ pe_max, const float* __restrict__ pe_sum,
    const float* __restrict__ pv_min, const float* __restrict__ pv_max, const float* __restrict__ pv_sum,
    const int* __restrict__ cbase, const int* __restrict__ vstart,
    const float* __restrict__ W1, const float* __restrict__ b1,
    const float* __restrict__ W2, const float* __restrict__ b2,
    float* __restrict__ out, int n_in, int n_hid, int n_out)
{
    __shared__ float row[576];
    __shared__ float h[256];
    int gi = blockIdx.x;
    int t = threadIdx.x;

    if (t < D) {
        float mn = INFINITY, mx = -INFINITY, sm = 0.f;
        #pragma unroll 8
        for (int s = 0; s < EBPS; ++s) {
            size_t o = ((size_t)gi * EBPS + s) * D + t;
            mn = fminf(mn, pe_min[o]); mx = fmaxf(mx, pe_max[o]); sm += pe_sum[o];
        }
        float cnt = (float)(cbase[gi + 1] - cbase[gi]);
        row[64 + t]  = mn;
        row[128 + t] = sm / fmaxf(cnt, 1.0f);
        row[192 + t] = sm;
        row[256 + t] = mx;

        float vmn = INFINITY, vmx = -INFINITY, vsm = 0.f;
        #pragma unroll
        for (int s = 0; s < VBPS; ++s) {
            size_t o = ((size_t)gi * VBPS + s) * D + t;
            vmn = fminf(vmn, pv_min[o]); vmx = fmaxf(vmx, pv_max[o]); vsm += pv_sum[o];
        }
        float vcnt = (float)(vstart[gi + 1] - vstart[gi]);
        row[320 + t] = vmn;
        row[384 + t] = vsm / fmaxf(vcnt, 1.0f);
        row[448 + t] = vsm;
        row[512 + t] = vmx;

        row[t] = g_in[gi * D + t];
    }
    __syncthreads();

    for (int j = t; j < n_hid; j += blockDim.x) {
        float acc = b1[j];
        #pragma unroll 8
        for (int k = 0; k < n_in; ++k) acc = fmaf(row[k], W1[k * n_hid + j], acc);
        h[j] = fmaxf(acc, 0.0f);
    }
    __syncthreads();

    for (int j = t; j < n_out; j += blockDim.x) {
        float acc = b2[j];
        #pragma unroll 8
        for (int k = 0; k < n_hid; ++k) acc = fmaf(h[k], W2[k * n_out + j], acc);
        out[gi * n_out + j] = acc;
    }
}

extern "C" void kernel_launch(void* const* d_in, const int* in_sizes, int n_in_args,
                              void* d_out, int out_size, void* d_ws, size_t ws_size,
                              hipStream_t stream) {
    const float* v_attr    = (const float*)d_in[0];
    const int*   edge_pair = (const int*)d_in[1];   // [2, E]; row 0 = src
    const float* e_attr    = (const float*)d_in[2];
    const float* g_in      = (const float*)d_in[3];
    const int*   batch     = (const int*)d_in[4];
    const float* W1        = (const float*)d_in[5];
    const float* b1        = (const float*)d_in[6];
    const float* W2        = (const float*)d_in[7];
    const float* b2        = (const float*)d_in[8];

    int N  = in_sizes[4];
    int E  = in_sizes[1] / 2;
    int nh = in_sizes[6];            // 256
    int no = in_sizes[8];            // 64
    int ni = in_sizes[5] / nh;       // 576

    // ---- ws bump allocation (256B aligned) ----
    char* p = (char*)d_ws;
    auto alloc = [&](size_t bytes) {
        char* r = p;
        p += (bytes + 255) & ~(size_t)255;
        return r;
    };
    unsigned char* eseg   = (unsigned char*)alloc((size_t)E);
    unsigned*      counts = (unsigned*)alloc((size_t)G_MAX * NB * 4);
    unsigned*      gtot   = (unsigned*)alloc((size_t)G_MAX * 4);
    int*           cbase  = (int*)alloc((size_t)(G_MAX + 1) * 4);
    int*           vstart = (int*)alloc((size_t)(G_MAX + 1) * 4);
    int*           s_eid  = (int*)alloc((size_t)E * 4);
    float*         pe_min = (float*)alloc((size_t)G_MAX * EBPS * D * 4);
    float*         pe_max = (float*)alloc((size_t)G_MAX * EBPS * D * 4);
    float*         pe_sum = (float*)alloc((size_t)G_MAX * EBPS * D * 4);
    float*         pv_min = (float*)alloc((size_t)G_MAX * VBPS * D * 4);
    float*         pv_max = (float*)alloc((size_t)G_MAX * VBPS * D * 4);
    float*         pv_sum = (float*)alloc((size_t)G_MAX * VBPS * D * 4);

    k_eseg_hist<<<NB, 256, 0, stream>>>(edge_pair, batch, E, eseg, counts);
    k_scan_counts<<<G_MAX, 256, 0, stream>>>(counts, gtot);
    k_bounds<<<1, 256, 0, stream>>>(gtot, batch, N, cbase, vstart);
    k_scatter<<<NB, 256, 0, stream>>>(eseg, counts, cbase, E, s_eid);

    // combined edge + vertex gather (edges: via sorted id list; vertices: contiguous)
    k_gather_stats<<<G_MAX * EBPS + G_MAX * VBPS, 256, 0, stream>>>(
        e_attr, s_eid, cbase, v_attr, vstart,
        pe_min, pe_max, pe_sum, pv_min, pv_max, pv_sum);

    k_finalize_mlp<<<G_MAX, 256, 0, stream>>>(g_in,
        pe_min, pe_max, pe_sum, pv_min, pv_max, pv_sum,
        cbase, vstart, W1, b1, W2, b2,
        (float*)d_out, ni, nh, no);
}